// Round 9
// baseline (136.672 us; speedup 1.0000x reference)
//
#include <hip/hip_runtime.h>

typedef unsigned short ushort_t;
typedef unsigned int uint_t;
typedef __attribute__((ext_vector_type(8))) short short8;
typedef __attribute__((ext_vector_type(2))) uint_t uint2v;
typedef __attribute__((ext_vector_type(2))) float float2v;
typedef __attribute__((ext_vector_type(4))) float float4v;

#define Bn 32
#define Nn 2048
#define Cn 8
#define Fn 128
#define On 128
// agg: bf16, K-major within 32-row tiles. Tile t = rows [32t, 32t+32).
// Element: agg[t*TILE_SHORTS + (unit*32 + row)*8 + e], unit in [0,48).
// Unit u holds k-indices [u*8, u*8+8) of the concat [self|r|l] (k in [0,384)).
// This makes pass-2's MFMA A-frag read 16-consecutive-lane (conflict-free)
// AND lets global_load_lds stage the tile contiguously (no padding needed).
#define TILE_SHORTS (32 * 384)

// float -> bf16 bits, round-to-nearest-even (used in prep only)
__device__ __forceinline__ ushort_t f2bf(float x) {
  unsigned u = __float_as_uint(x);
  u += 0x7fffu + ((u >> 16) & 1u);
  return (ushort_t)(u >> 16);
}

// pack two floats -> two truncated bf16 in one v_perm (lo -> low short)
__device__ __forceinline__ uint_t pk2bf(float lo, float hi) {
  return __builtin_amdgcn_perm(__float_as_uint(hi), __float_as_uint(lo),
                               0x07060302u);
}

// Merged prep: blocks [0,24): W fragment pack; blocks [24,280): coefs.
// wsw: fragment q (0..7), step ks (0..11): ((q*12+ks)*64 + lane)*8 + j holds
// W[k][col], col = q*16 + (lane&15), k = (lane>>4)*8 + ks*32 + j.
// coefb[g*16 + 2c] = cr_c, [+1] = cl_c (pre-masked).
__global__ __launch_bounds__(256)
void prep_kernel(const float* __restrict__ w_t, const float* __restrict__ w_l,
                 const float* __restrict__ w_r, const int* __restrict__ children,
                 ushort_t* __restrict__ wsw, float* __restrict__ coefb) {
  if (blockIdx.x < 24) {
    int t = blockIdx.x * 256 + threadIdx.x;  // one short8 per thread
    int lane = t & 63;
    int r = t >> 6;  // 0..95
    int ks = r % 12;
    int q = r / 12;  // 0..7
    int col = q * 16 + (lane & 15);
    int kbase = ((lane >> 4) * 8) + ks * 32;
    ushort_t* dst = wsw + (size_t)t * 8;
#pragma unroll
    for (int j = 0; j < 8; ++j) {
      int k = kbase + j;
      const float* src = (k < Fn) ? w_t : (k < 2 * Fn) ? w_r : w_l;
      int f = k & (Fn - 1);
      dst[j] = f2bf(src[f * On + col]);
    }
  } else {
    int g = (blockIdx.x - 24) * 256 + threadIdx.x;  // row in [0, 65536)
    const int4* chv = (const int4*)(children + (size_t)g * Cn);
    int4 ca = chv[0], cb = chv[1];
    int idx[Cn] = {ca.x, ca.y, ca.z, ca.w, cb.x, cb.y, cb.z, cb.w};
    int ns = 0;
#pragma unroll
    for (int c = 0; c < Cn; ++c) ns += (idx[c] != 0);
    const float denom = (ns > 1) ? (float)(ns - 1) : 1.0f;
    float o[16];
#pragma unroll
    for (int c = 0; c < Cn; ++c) {
      float m = (idx[c] != 0) ? 1.0f : 0.0f;
      float cr0 = (ns == 1) ? ((c == 0) ? 0.5f : 0.0f) : ((float)c / denom);
      float cr = cr0 * m;
      o[2 * c] = cr;
      o[2 * c + 1] = (1.0f - cr) * m;
    }
    float4v* dst = (float4v*)(coefb + (size_t)g * 16);
#pragma unroll
    for (int j = 0; j < 4; ++j) {
      float4v v = {o[4 * j], o[4 * j + 1], o[4 * j + 2], o[4 * j + 3]};
      dst[j] = v;
    }
  }
}

// ---------------- Pass 1: gather + combine -> agg (K-major tiles) ----------
// No LDS, no barriers, lean VALU. One thread = one (row, float4 chunk).
__global__ __launch_bounds__(256)
void pass1_kernel(const float* __restrict__ nodes,
                  const int* __restrict__ children,
                  const float* __restrict__ coefb,
                  ushort_t* __restrict__ agg) {
  const int tid = threadIdx.x;
  // XCD swizzle (8192 blocks): XCD k (round-robin %8) owns contiguous rows
  // [k*8192,(k+1)*8192) = 4 batches = 4 MB of nodes -> its L2.
  const int sb = ((blockIdx.x & 7) << 10) | (blockIdx.x >> 3);
  const int rb0 = sb * 8;
  const int g = rb0 + (tid >> 5);
  const int ln = tid & 31;
  const int batch_row0 = rb0 & ~(Nn - 1);  // block-uniform -> SGPR
  const float* nb = nodes + (size_t)batch_row0 * Fn;

  // children + coefs: same-address broadcast loads within each 32-lane group
  const int4* chv = (const int4*)(children + (size_t)g * Cn);
  int4 ca = chv[0], cb = chv[1];
  const float4v* cfp = (const float4v*)(coefb + (size_t)g * 16);
  float4v cf[4] = {cfp[0], cfp[1], cfp[2], cfp[3]};

  const float4v sv = *((const float4v*)(nodes + (size_t)g * Fn) + ln);

  int idx[Cn] = {ca.x, ca.y, ca.z, ca.w, cb.x, cb.y, cb.z, cb.w};
  float4v gv[Cn];
#pragma unroll
  for (int c = 0; c < Cn; ++c) {
    // clamp: replay/fault-safe; no-op for valid inputs (coef already masked)
    gv[c] = *((const float4v*)(nb + (size_t)(idx[c] & (Nn - 1)) * Fn) + ln);
  }

  float2v rl0 = {0.f, 0.f}, rl1 = {0.f, 0.f}, rl2 = {0.f, 0.f}, rl3 = {0.f, 0.f};
#pragma unroll
  for (int c = 0; c < Cn; ++c) {
    const float2v cc = {cf[c >> 1][(c & 1) * 2], cf[c >> 1][(c & 1) * 2 + 1]};
    const float4v v = gv[c];
    rl0 += (float2v){v.x, v.x} * cc;
    rl1 += (float2v){v.y, v.y} * cc;
    rl2 += (float2v){v.z, v.z} * cc;
    rl3 += (float2v){v.w, v.w} * cc;
  }

  // K-major store: unit = sec*16 + (ln>>1); shorts (unit*32 + row)*8 + (ln&1)*4
  ushort_t* ap = agg + (size_t)(g >> 5) * TILE_SHORTS + (g & 31) * 8 + (ln & 1) * 4;
  const int ub = (ln >> 1) * 256;  // unit stride = 32 rows * 8 shorts
  *(uint2v*)(ap + ub) = (uint2v){pk2bf(sv.x, sv.y), pk2bf(sv.z, sv.w)};
  *(uint2v*)(ap + ub + 16 * 256) =
      (uint2v){pk2bf(rl0.x, rl1.x), pk2bf(rl2.x, rl3.x)};
  *(uint2v*)(ap + ub + 32 * 256) =
      (uint2v){pk2bf(rl0.y, rl1.y), pk2bf(rl2.y, rl3.y)};
}

// ---------------- Pass 2: dense GEMM out = relu(agg @ W + b) ----------------
// 32-row x 128-col blocks; A tile staged via global_load_lds (width 16);
// conflict-free unit-major ds_reads; B streamed per col-tile (48 VGPRs).
__global__ __launch_bounds__(256)
void pass2_kernel(const ushort_t* __restrict__ agg,
                  const ushort_t* __restrict__ wsw,
                  const float* __restrict__ bias,
                  float* __restrict__ out) {
  __shared__ __align__(16) ushort_t tile[TILE_SHORTS];  // 24576 B

  const int tid = threadIdx.x;
  const int lane = tid & 63;
  const int wave = tid >> 6;
  const int l15 = lane & 15;
  const int quad = lane >> 4;
  // Same XCD mapping as pass-1 writers: tile b lives on XCD (b>>8)&7's L2.
  const int b = ((blockIdx.x & 7) << 8) | (blockIdx.x >> 3);
  const int rb0 = b * 32;

  // Stage 24 KB tile: 24 x (64 lanes x 16 B) contiguous, 6 per wave.
  const uint_t* gsrc = (const uint_t*)(agg + (size_t)b * TILE_SHORTS);
#pragma unroll
  for (int it = 0; it < 6; ++it) {
    const int unit1k = wave * 6 + it;  // 1-KB chunk index
    __builtin_amdgcn_global_load_lds(
        (const __attribute__((address_space(1))) uint_t*)(gsrc + unit1k * 256 +
                                                          lane * 4),
        (__attribute__((address_space(3))) uint_t*)(uint_t*)(void*)(
            tile + unit1k * 512),
        16, 0, 0);
  }

  __syncthreads();

#pragma unroll
  for (int ct = 0; ct < 2; ++ct) {
    const int q = wave * 2 + ct;
    short8 bfrag[12];  // streamed from L2-hot wsw, 1 KB/wave/step
#pragma unroll
    for (int ks = 0; ks < 12; ++ks)
      bfrag[ks] = ((const short8*)wsw)[(q * 12 + ks) * 64 + lane];

    const int col = q * 16 + l15;
    const float bb = bias[col];

#pragma unroll
    for (int st = 0; st < 2; ++st) {
      float4v acc = {0.f, 0.f, 0.f, 0.f};
#pragma unroll
      for (int ks = 0; ks < 12; ++ks) {
        // A[m = st*16+l15][k = ks*32+quad*8+j] lives at unit ks*4+quad
        const short8 af =
            *(const short8*)(tile + ((ks * 4 + quad) * 32 + st * 16 + l15) * 8);
        acc = __builtin_amdgcn_mfma_f32_16x16x32_bf16(af, bfrag[ks], acc, 0, 0, 0);
      }
      const int grow = rb0 + st * 16 + quad * 4;
#pragma unroll
      for (int r2 = 0; r2 < 4; ++r2)
        out[(size_t)(grow + r2) * On + col] = fmaxf(acc[r2] + bb, 0.f);
    }
  }
}

extern "C" void kernel_launch(void* const* d_in, const int* in_sizes, int n_in,
                              void* d_out, int out_size, void* d_ws, size_t ws_size,
                              hipStream_t stream) {
  const float* nodes = (const float*)d_in[0];
  const int* children = (const int*)d_in[1];
  const float* w_t = (const float*)d_in[2];
  const float* w_l = (const float*)d_in[3];
  const float* w_r = (const float*)d_in[4];
  const float* bias = (const float*)d_in[5];
  float* out = (float*)d_out;

  ushort_t* agg = (ushort_t*)d_ws;                                // 48 MiB
  ushort_t* wsw = (ushort_t*)((char*)d_ws + ((size_t)64 << 20));  // 96 KiB
  float* coefb = (float*)((char*)d_ws + ((size_t)80 << 20));      // 4 MiB

  prep_kernel<<<280, 256, 0, stream>>>(w_t, w_l, w_r, children, wsw, coefb);
  pass1_kernel<<<(Bn * Nn) / 8, 256, 0, stream>>>(nodes, children, coefb, agg);
  pass2_kernel<<<(Bn * Nn) / 32, 256, 0, stream>>>(agg, wsw, bias, out);
}

// Round 10
// 118.275 us; speedup vs baseline: 1.1555x; 1.1555x over previous
//
#include <hip/hip_runtime.h>

typedef unsigned short ushort_t;
typedef unsigned int uint_t;
typedef __attribute__((ext_vector_type(8))) short short8;
typedef __attribute__((ext_vector_type(4))) uint_t uint4v;
typedef __attribute__((ext_vector_type(2))) float float2v;
typedef __attribute__((ext_vector_type(4))) float float4v;

#define Bn 32
#define Nn 2048
#define Cn 8
#define Fn 128
#define On 128
#define MT 16    // rows per block
#define LDSK 392 // padded LDS row stride in shorts (784 B = 49 x 16 B)

// float -> bf16 bits, round-to-nearest-even (prep only)
__device__ __forceinline__ ushort_t f2bf(float x) {
  unsigned u = __float_as_uint(x);
  u += 0x7fffu + ((u >> 16) & 1u);
  return (ushort_t)(u >> 16);
}

// two floats -> two truncated bf16 in ONE v_perm (lo -> low short).
// Empirically absmax-neutral vs RNE on this problem (R9: 0.03125).
__device__ __forceinline__ uint_t pk2bf(float lo, float hi) {
  return __builtin_amdgcn_perm(__float_as_uint(hi), __float_as_uint(lo),
                               0x07060302u);
}

// W fragments: q (0..7), ks (0..11): ((q*12+ks)*64 + lane)*8 + j holds
// W[k][col], col = q*16 + (lane&15), k = (lane>>4)*8 + ks*32 + j.
__global__ void prep_w_kernel(const float* __restrict__ w_t,
                              const float* __restrict__ w_l,
                              const float* __restrict__ w_r,
                              ushort_t* __restrict__ wsw) {
  int t = blockIdx.x * blockDim.x + threadIdx.x;  // one short8 per thread
  if (t >= 6144) return;
  int lane = t & 63;
  int r = t >> 6;  // 0..95
  int ks = r % 12;
  int q = r / 12;  // 0..7
  int col = q * 16 + (lane & 15);
  int kbase = ((lane >> 4) * 8) + ks * 32;
  ushort_t* dst = wsw + (size_t)t * 8;
#pragma unroll
  for (int j = 0; j < 8; ++j) {
    int k = kbase + j;
    const float* src = (k < Fn) ? w_t : (k < 2 * Fn) ? w_r : w_l;
    int f = k & (Fn - 1);
    dst[j] = f2bf(src[f * On + col]);
  }
}

__global__ __launch_bounds__(256)
void tree_conv_kernel(const float* __restrict__ nodes,
                      const int* __restrict__ children,
                      const ushort_t* __restrict__ wsw,
                      const float* __restrict__ bias,
                      float* __restrict__ out) {
  __shared__ __align__(16) ushort_t agg[MT * LDSK];  // 12544 B

  const int tid = threadIdx.x;
  // XCD swizzle (4096 blocks): XCD k (round-robin %8) owns sb [512k,512k+512)
  // = rows [8192k, 8192k+8192) = batches 4k..4k+3 (4 MB nodes -> its L2).
  const int sb = ((blockIdx.x & 7) << 9) | (blockIdx.x >> 3);
  const int rb0 = sb * MT;

  // ------- Phase A: 16 threads/row, 8 floats each; lean VALU ----------------
  {
    const int row = tid >> 4;  // 0..15
    const int ln = tid & 15;   // floats [ln*8, ln*8+8)
    const int g = rb0 + row;
    const int base_row = g & ~(Nn - 1);

    const int4* chv = (const int4*)(children + (size_t)g * Cn);
    int4 ca = chv[0], cb = chv[1];
    int idx[Cn] = {ca.x, ca.y, ca.z, ca.w, cb.x, cb.y, cb.z, cb.w};

    int ns = 0;
#pragma unroll
    for (int c = 0; c < Cn; ++c) ns += (idx[c] != 0);
    // lean coef: one rcp; 1/ns-1 exact enough (rel err ~1e-7)
    const float rden = __builtin_amdgcn_rcpf((ns > 1) ? (float)(ns - 1) : 1.0f);
    const bool single = (ns == 1);

    float crv[Cn], clv[Cn];
#pragma unroll
    for (int c = 0; c < Cn; ++c) {
      float m = (idx[c] != 0) ? 1.0f : 0.0f;
      float cr0 = single ? ((c == 0) ? 0.5f : 0.0f) : ((float)c * rden);
      float cr = cr0 * m;
      crv[c] = cr;
      clv[c] = (1.0f - cr) * m;
      idx[c] &= (Nn - 1);  // replay/fault-safe clamp; no-op for valid inputs
    }

    const float4v* sp = (const float4v*)(nodes + (size_t)g * Fn) + ln * 2;
    const float4v s0 = sp[0], s1 = sp[1];

    float2v rl[8];
#pragma unroll
    for (int e = 0; e < 8; ++e) rl[e] = (float2v){0.f, 0.f};

#pragma unroll
    for (int c = 0; c < Cn; ++c) {
      const float4v* cp =
          (const float4v*)(nodes + (size_t)(base_row + idx[c]) * Fn) + ln * 2;
      const float4v v0 = cp[0], v1 = cp[1];
      const float2v cc = {crv[c], clv[c]};  // (r,l) pair -> v_pk_fma_f32
      rl[0] += (float2v){v0.x, v0.x} * cc;
      rl[1] += (float2v){v0.y, v0.y} * cc;
      rl[2] += (float2v){v0.z, v0.z} * cc;
      rl[3] += (float2v){v0.w, v0.w} * cc;
      rl[4] += (float2v){v1.x, v1.x} * cc;
      rl[5] += (float2v){v1.y, v1.y} * cc;
      rl[6] += (float2v){v1.z, v1.z} * cc;
      rl[7] += (float2v){v1.w, v1.w} * cc;
    }

    ushort_t* arow = agg + row * LDSK + ln * 8;
    *(uint4v*)(arow) = (uint4v){pk2bf(s0.x, s0.y), pk2bf(s0.z, s0.w),
                                pk2bf(s1.x, s1.y), pk2bf(s1.z, s1.w)};
    *(uint4v*)(arow + Fn) =
        (uint4v){pk2bf(rl[0].x, rl[1].x), pk2bf(rl[2].x, rl[3].x),
                 pk2bf(rl[4].x, rl[5].x), pk2bf(rl[6].x, rl[7].x)};
    *(uint4v*)(arow + 2 * Fn) =
        (uint4v){pk2bf(rl[0].y, rl[1].y), pk2bf(rl[2].y, rl[3].y),
                 pk2bf(rl[4].y, rl[5].y), pk2bf(rl[6].y, rl[7].y)};
  }

  __syncthreads();

  // ------- Phase B: 4 waves x 2 sequential col-tiles (no cross-barrier hoist)
  const int lane = tid & 63;
  const int wave = tid >> 6;
  const int l15 = lane & 15;
  const int quad = lane >> 4;
  const ushort_t* ar = agg + l15 * LDSK + quad * 8;

#pragma unroll
  for (int ct = 0; ct < 2; ++ct) {
    const int q = wave * 2 + ct;
    short8 bfrag[12];  // 48 VGPRs, streamed from L2-hot wsw
#pragma unroll
    for (int ks = 0; ks < 12; ++ks)
      bfrag[ks] = ((const short8*)wsw)[(q * 12 + ks) * 64 + lane];

    const int col = q * 16 + l15;
    const float bb = bias[col];

    float4v acc = {0.f, 0.f, 0.f, 0.f};
#pragma unroll
    for (int ks = 0; ks < 12; ++ks) {
      const short8 af = *(const short8*)(ar + ks * 32);
      acc = __builtin_amdgcn_mfma_f32_16x16x32_bf16(af, bfrag[ks], acc, 0, 0, 0);
    }
    const int grow = rb0 + quad * 4;
#pragma unroll
    for (int r2 = 0; r2 < 4; ++r2)
      out[(size_t)(grow + r2) * On + col] = fmaxf(acc[r2] + bb, 0.f);
  }
}

extern "C" void kernel_launch(void* const* d_in, const int* in_sizes, int n_in,
                              void* d_out, int out_size, void* d_ws, size_t ws_size,
                              hipStream_t stream) {
  const float* nodes = (const float*)d_in[0];
  const int* children = (const int*)d_in[1];
  const float* w_t = (const float*)d_in[2];
  const float* w_l = (const float*)d_in[3];
  const float* w_r = (const float*)d_in[4];
  const float* bias = (const float*)d_in[5];
  float* out = (float*)d_out;
  ushort_t* wsw = (ushort_t*)d_ws;  // 96 KiB, fragment-swizzled

  prep_w_kernel<<<24, 256, 0, stream>>>(w_t, w_l, w_r, wsw);
  tree_conv_kernel<<<(Bn * Nn) / MT, 256, 0, stream>>>(nodes, children, wsw,
                                                       bias, out);
}